// Round 12
// baseline (97.886 us; speedup 1.0000x reference)
//
#include <hip/hip_runtime.h>
#include <math.h>

#define N_QUBITS 4
#define N_LAYERS 6
#define NW (N_LAYERS * N_QUBITS)

// POD vector type that maps to an SGPR quad under the "s" asm constraint.
typedef float v4sf __attribute__((ext_vector_type(4)));

// ---------------------------------------------------------------------------
// Prep kernel (1 block): build W (16x16 complex) from the 24 RX gates + CNOT
// rings, form S_q = Re(W^dag Z_q W), contract to the 81-term multilinear table
//   out_q(x) = sum_{t in {I,Z,X}^4} C_q[t] * prod_p (1, cos x_p, sin x_p)[t_p]
// Layout: Ctab[t*4 + q]  (float4 per term t -> one scalar load feeds 4 outputs).
// Unchanged from R8 (known good).
// ---------------------------------------------------------------------------
__global__ __launch_bounds__(256) void qprep_kernel(
    const float* __restrict__ weights, float* __restrict__ Ctab)
{
    __shared__ float Wr[16][16];
    __shared__ float Wi[16][16];
    __shared__ float S[4][16][16];
    __shared__ float wc[NW], ws[NW];
    const int tid = threadIdx.x;
    if (tid < NW) {
        float t = weights[tid] * 0.5f;
        wc[tid] = __cosf(t);
        ws[tid] = __sinf(t);
    }
    __syncthreads();

    if (tid < 16) {
        float re[16], im[16];
#pragma unroll
        for (int k = 0; k < 16; ++k) { re[k] = (k == tid) ? 1.f : 0.f; im[k] = 0.f; }
#pragma unroll 1
        for (int l = 0; l < N_LAYERS; ++l) {
#pragma unroll
            for (int q = 0; q < 4; ++q) {
                const float ct = wc[l * 4 + q], sn = ws[l * 4 + q];
                const int mask = 8 >> q;
#pragma unroll
                for (int idx = 0; idx < 16; ++idx) {
                    if (idx & mask) continue;
                    const int j = idx | mask;
                    float r0 = re[idx], u0 = im[idx], r1 = re[j], u1 = im[j];
                    re[idx] = ct * r0 + sn * u1; im[idx] = ct * u0 - sn * r1;
                    re[j]   = ct * r1 + sn * u0; im[j]   = ct * u1 - sn * r0;
                }
            }
#pragma unroll
            for (int q = 0; q < 4; ++q) {
                const int cm = 8 >> q, tm = 8 >> ((q + 1) & 3);
#pragma unroll
                for (int idx = 0; idx < 16; ++idx) {
                    if ((idx & cm) && !(idx & tm)) {
                        const int j = idx | tm;
                        float t0 = re[idx]; re[idx] = re[j]; re[j] = t0;
                        float t1 = im[idx]; im[idx] = im[j]; im[j] = t1;
                    }
                }
            }
        }
#pragma unroll
        for (int k = 0; k < 16; ++k) { Wr[k][tid] = re[k]; Wi[k][tid] = im[k]; }
    }
    __syncthreads();

    {
        const int i = tid >> 4, j = tid & 15;
        float a0 = 0.f, a1 = 0.f, a2 = 0.f, a3 = 0.f;
#pragma unroll
        for (int k = 0; k < 16; ++k) {
            const float p = Wr[k][i] * Wr[k][j] + Wi[k][i] * Wi[k][j];
            a0 += (k & 8) ? -p : p;
            a1 += (k & 4) ? -p : p;
            a2 += (k & 2) ? -p : p;
            a3 += (k & 1) ? -p : p;
        }
        S[0][i][j] = a0; S[1][i][j] = a1; S[2][i][j] = a2; S[3][i][j] = a3;
    }
    __syncthreads();

    if (tid < 81) {
        const int t1 = tid / 27, t2 = (tid / 9) % 3, t3 = (tid / 3) % 3, t4 = tid % 3;
        int zm = 0, xm = 0;
        if (t1 == 1) zm |= 8; else if (t1 == 2) xm |= 8;
        if (t2 == 1) zm |= 4; else if (t2 == 2) xm |= 4;
        if (t3 == 1) zm |= 2; else if (t3 == 2) xm |= 2;
        if (t4 == 1) zm |= 1; else if (t4 == 2) xm |= 1;
#pragma unroll
        for (int q = 0; q < 4; ++q) {
            float acc = 0.f;
#pragma unroll
            for (int i = 0; i < 16; ++i) {
                const float v = S[q][i][i ^ xm];
                acc += (__popc(i & zm) & 1) ? -v : v;
            }
            Ctab[tid * 4 + q] = acc * 0.0625f;
        }
    }
}

// ---------------------------------------------------------------------------
// Main kernel: out4 = sum_i u9[i] * ( sum_j C4[i*9+j] * w9[j] ).
// Coefficients fetched with FORCED scalar loads: inline-asm s_load_dwordx4
// into SGPR quads (16 B per WAVE via the scalar cache) instead of per-lane
// vector loads whose broadcast returns (16 B x 64 lanes per load) are the
// ~18 us wall seen across R2/R5/R6/R8/R9.
// FIX vs R11 (which memory-faulted): "=&s" EARLY-CLOBBER on every output so
// the register allocator cannot alias an output quad with the still-needed
// address pair input — R11's plain "=s" allowed exactly that aliasing.
// waitcnt is bundled in the same asm so consuming FMAs can't float above it.
// Every consuming op is v_fma(dst, sgpr, vgpr, vgpr): 1 SGPR operand, legal.
// ---------------------------------------------------------------------------
#define QBLOCK(I)                                                             \
    do {                                                                      \
        v4sf c0, c1, c2, c3, c4, c5, c6, c7, c8;                              \
        asm volatile(                                                         \
            "s_load_dwordx4 %0, %9, %10\n\t"                                  \
            "s_load_dwordx4 %1, %9, %11\n\t"                                  \
            "s_load_dwordx4 %2, %9, %12\n\t"                                  \
            "s_load_dwordx4 %3, %9, %13\n\t"                                  \
            "s_load_dwordx4 %4, %9, %14\n\t"                                  \
            "s_load_dwordx4 %5, %9, %15\n\t"                                  \
            "s_load_dwordx4 %6, %9, %16\n\t"                                  \
            "s_load_dwordx4 %7, %9, %17\n\t"                                  \
            "s_load_dwordx4 %8, %9, %18\n\t"                                  \
            "s_waitcnt lgkmcnt(0)"                                            \
            : "=&s"(c0), "=&s"(c1), "=&s"(c2), "=&s"(c3), "=&s"(c4),          \
              "=&s"(c5), "=&s"(c6), "=&s"(c7), "=&s"(c8)                      \
            : "s"(Ctab),                                                      \
              "i"((I) * 144 + 0),  "i"((I) * 144 + 16), "i"((I) * 144 + 32),  \
              "i"((I) * 144 + 48), "i"((I) * 144 + 64), "i"((I) * 144 + 80),  \
              "i"((I) * 144 + 96), "i"((I) * 144 + 112),"i"((I) * 144 + 128));\
        float tx = 0.f, ty = 0.f, tz = 0.f, tw = 0.f;                         \
        tx = fmaf(c0[0], w9[0], tx); ty = fmaf(c0[1], w9[0], ty);             \
        tz = fmaf(c0[2], w9[0], tz); tw = fmaf(c0[3], w9[0], tw);             \
        tx = fmaf(c1[0], w9[1], tx); ty = fmaf(c1[1], w9[1], ty);             \
        tz = fmaf(c1[2], w9[1], tz); tw = fmaf(c1[3], w9[1], tw);             \
        tx = fmaf(c2[0], w9[2], tx); ty = fmaf(c2[1], w9[2], ty);             \
        tz = fmaf(c2[2], w9[2], tz); tw = fmaf(c2[3], w9[2], tw);             \
        tx = fmaf(c3[0], w9[3], tx); ty = fmaf(c3[1], w9[3], ty);             \
        tz = fmaf(c3[2], w9[3], tz); tw = fmaf(c3[3], w9[3], tw);             \
        tx = fmaf(c4[0], w9[4], tx); ty = fmaf(c4[1], w9[4], ty);             \
        tz = fmaf(c4[2], w9[4], tz); tw = fmaf(c4[3], w9[4], tw);             \
        tx = fmaf(c5[0], w9[5], tx); ty = fmaf(c5[1], w9[5], ty);             \
        tz = fmaf(c5[2], w9[5], tz); tw = fmaf(c5[3], w9[5], tw);             \
        tx = fmaf(c6[0], w9[6], tx); ty = fmaf(c6[1], w9[6], ty);             \
        tz = fmaf(c6[2], w9[6], tz); tw = fmaf(c6[3], w9[6], tw);             \
        tx = fmaf(c7[0], w9[7], tx); ty = fmaf(c7[1], w9[7], ty);             \
        tz = fmaf(c7[2], w9[7], tz); tw = fmaf(c7[3], w9[7], tw);             \
        tx = fmaf(c8[0], w9[8], tx); ty = fmaf(c8[1], w9[8], ty);             \
        tz = fmaf(c8[2], w9[8], tz); tw = fmaf(c8[3], w9[8], tw);             \
        const float u = u9[I];                                                \
        ox = fmaf(tx, u, ox); oy = fmaf(ty, u, oy);                           \
        oz = fmaf(tz, u, oz); ow = fmaf(tw, u, ow);                           \
    } while (0)

__global__ __launch_bounds__(256, 8) void qeval_kernel(
    const float* __restrict__ x, const float* __restrict__ Ctab,
    float* __restrict__ out, int B)
{
    int b = blockIdx.x * 256 + threadIdx.x;
    b = (b < B) ? b : (B - 1);   // clamp: wave-uniform control flow

    const float4 xv = reinterpret_cast<const float4*>(x)[b];
    const float c0 = __cosf(xv.x), s0 = __sinf(xv.x);
    const float c1 = __cosf(xv.y), s1 = __sinf(xv.y);
    const float c2 = __cosf(xv.z), s2 = __sinf(xv.z);
    const float c3 = __cosf(xv.w), s3 = __sinf(xv.w);

    float u9[9], w9[9];
    u9[0] = 1.f;  u9[1] = c1;      u9[2] = s1;
    u9[3] = c0;   u9[4] = c0 * c1; u9[5] = c0 * s1;
    u9[6] = s0;   u9[7] = s0 * c1; u9[8] = s0 * s1;
    w9[0] = 1.f;  w9[1] = c3;      w9[2] = s3;
    w9[3] = c2;   w9[4] = c2 * c3; w9[5] = c2 * s3;
    w9[6] = s2;   w9[7] = s2 * c3; w9[8] = s2 * s3;

    float ox = 0.f, oy = 0.f, oz = 0.f, ow = 0.f;
    QBLOCK(0); QBLOCK(1); QBLOCK(2);
    QBLOCK(3); QBLOCK(4); QBLOCK(5);
    QBLOCK(6); QBLOCK(7); QBLOCK(8);

    reinterpret_cast<float4*>(out)[b] = make_float4(ox, oy, oz, ow);
}

extern "C" void kernel_launch(void* const* d_in, const int* in_sizes, int n_in,
                              void* d_out, int out_size, void* d_ws, size_t ws_size,
                              hipStream_t stream) {
    const float* x = (const float*)d_in[0];
    const float* weights = (const float*)d_in[1];
    float* out = (float*)d_out;
    float* Ctab = (float*)d_ws;   // 324 floats, float4-per-term
    const int B = in_sizes[0] / 4;

    qprep_kernel<<<1, 256, 0, stream>>>(weights, Ctab);

    const int grid = (B + 255) / 256;
    qeval_kernel<<<grid, 256, 0, stream>>>(x, Ctab, out, B);
}